// Round 6
// baseline (1080.721 us; speedup 1.0000x reference)
//
#include <hip/hip_runtime.h>
#include <cstdint>
#include <cstddef>

typedef unsigned short u16;
typedef __bf16 bf16_t;
typedef bf16_t bf16x8 __attribute__((ext_vector_type(8)));
typedef float f32x4 __attribute__((ext_vector_type(4)));

#define NLAY 4
#define DMODEL 1280
#define NHEAD 16
#define HDIM 80
#define HDP 96           // padded head dim for QK^T K-loop (3 x 32)
#define MLPD 5120
#define LTOK 2048
#define SEGLEN 512

__device__ __forceinline__ u16 f2bf(float f) {
  union { float f; unsigned u; } x; x.f = f;
  unsigned r = x.u + 0x7fffu + ((x.u >> 16) & 1u);
  return (u16)(r >> 16);
}
__device__ __forceinline__ float bf2f(u16 s) {
  union { unsigned u; float f; } x; x.u = ((unsigned)s) << 16;
  return x.f;
}

#define GLOAD_LDS16(gsrc, ldst) \
  __builtin_amdgcn_global_load_lds((const __attribute__((address_space(1))) void*)(gsrc), \
                                   (__attribute__((address_space(3))) void*)(ldst), 16, 0, 0)

// ---------------- all-weights fp32 -> bf16 convert (one layer, one kernel) ----------------
#define C0 (3 * DMODEL * DMODEL / 4)          // qkv_w float4s
#define C1 (C0 + DMODEL * DMODEL / 4)         // + proj_w
#define C2 (C1 + MLPD * DMODEL / 4)           // + mlp_w1
#define C3 (C2 + DMODEL * MLPD / 4)           // + mlp_w2
__global__ __launch_bounds__(256) void cvt4(const float* __restrict__ s_q,
                                            const float* __restrict__ s_p,
                                            const float* __restrict__ s_1,
                                            const float* __restrict__ s_2,
                                            u16* __restrict__ o_q, u16* __restrict__ o_p,
                                            u16* __restrict__ o_1, u16* __restrict__ o_2) {
  int i = blockIdx.x * 256 + threadIdx.x;
  const float* src; u16* dst; int off;
  if (i < C0)      { src = s_q; dst = o_q; off = i; }
  else if (i < C1) { src = s_p; dst = o_p; off = i - C0; }
  else if (i < C2) { src = s_1; dst = o_1; off = i - C1; }
  else if (i < C3) { src = s_2; dst = o_2; off = i - C2; }
  else return;
  const float4 v = reinterpret_cast<const float4*>(src)[off];
  union { u16 s[4]; uint2 u; } o;
  o.s[0] = f2bf(v.x); o.s[1] = f2bf(v.y); o.s[2] = f2bf(v.z); o.s[3] = f2bf(v.w);
  reinterpret_cast<uint2*>(dst)[off] = o.u;
}

// ---------------- LayerNorm (fp32 in, bf16 out) ----------------
__global__ __launch_bounds__(256) void ln_bf16(const float* __restrict__ x,
                                               const float* __restrict__ g,
                                               const float* __restrict__ b,
                                               u16* __restrict__ out) {
  int row = blockIdx.x;
  int t = threadIdx.x;
  const float* xr = x + (size_t)row * DMODEL;
  float v[5]; float s = 0.f, s2 = 0.f;
#pragma unroll
  for (int i = 0; i < 5; i++) { v[i] = xr[t + i * 256]; s += v[i]; s2 += v[i] * v[i]; }
#pragma unroll
  for (int off = 32; off; off >>= 1) { s += __shfl_down(s, off); s2 += __shfl_down(s2, off); }
  __shared__ float ps[4], ps2[4];
  int w = t >> 6;
  if ((t & 63) == 0) { ps[w] = s; ps2[w] = s2; }
  __syncthreads();
  s = ps[0] + ps[1] + ps[2] + ps[3];
  s2 = ps2[0] + ps2[1] + ps2[2] + ps2[3];
  float mean = s * (1.f / DMODEL);
  float var = s2 * (1.f / DMODEL) - mean * mean;
  float inv = rsqrtf(var + 1e-6f);
#pragma unroll
  for (int i = 0; i < 5; i++) {
    int c = t + i * 256;
    out[(size_t)row * DMODEL + c] = f2bf((v[i] - mean) * inv * g[c] + b[c]);
  }
}

// ---------------- GEMM: C[M,N] = A[M,K](bf16) @ B[N,K](bf16)^T + bias ----------------
// Tile: BM x BN, BK = 64 (round-3-proven zero-conflict swizzle). 2-phase
// prefetch double-buffer. Split-K via blockIdx.z: each z handles KC columns
// starting at z*KC; EPI 4 accumulates atomically (bias added by z==0 only).
// 64x64 tiles = 32 KB LDS -> 5 blocks/CU resident (vs 2 at 128x128).
// EPI 0: Cf = val + bias          (fp32 out)
// EPI 1: Cf += val + bias         (residual accumulate, fp32, single-K only)
// EPI 2: Cb = gelu(val + bias)    (bf16 out, fast __expf form)
// EPI 3: Cb = val + bias          (bf16 out)
// EPI 4: atomicAdd(Cf, val [+ bias if z==0])   (split-K residual accumulate)
template <int EPI, int BM, int BN>
__global__ __launch_bounds__(256) void gemm_bt(const u16* __restrict__ A,
                                               const u16* __restrict__ B,
                                               const float* __restrict__ bias,
                                               float* __restrict__ Cf,
                                               u16* __restrict__ Cb,
                                               int M, int N, int K, int KC) {
  constexpr int MI = BM / 32;            // A-frags per wave in M
  constexpr int NJ = BN / 32;            // B-frags per wave in N
  constexpr int ACH = BM * 64 / (256 * 8);  // A staging chunks per thread
  constexpr int BCH = BN * 64 / (256 * 8);  // B staging chunks per thread
  __shared__ u16 As[2][BM * 64];
  __shared__ u16 Bs[2][BN * 64];

  // bijective XCD-chunked block swizzle; within a chunk M-tiles run fastest
  int gN = gridDim.x, gM = gridDim.y;
  int flat = blockIdx.x + gN * blockIdx.y;
  int nwg = gN * gM;
  int qc = nwg >> 3, rc = nwg & 7;
  int xcd = flat & 7, pos = flat >> 3;
  int start = (xcd < rc) ? xcd * (qc + 1) : rc * (qc + 1) + (xcd - rc) * qc;
  int swz = start + pos;
  int m0 = (swz % gM) * BM;
  int n0 = (swz / gM) * BN;
  int kbase = blockIdx.z * KC;

  int t = threadIdx.x, lane = t & 63, w = t >> 6;
  int wm = w >> 1, wn = w & 1;
  int r = lane & 15, kq = lane >> 4;
  f32x4 acc[MI][NJ] = {};

  // staging: linear LDS dest (global_load_lds requirement), source slot
  // pre-swizzled with (row&7) so that swizzled ds_read is conflict-free
  auto stage = [&](int buf, int k0) {
#pragma unroll
    for (int i = 0; i < ACH; i++) {
      int chunk = i * 256 + t;
      int row = chunk >> 3, s = chunk & 7;
      int ss = s ^ (row & 7);
      GLOAD_LDS16(A + (size_t)(m0 + row) * K + k0 + ss * 8, &As[buf][chunk * 8]);
    }
#pragma unroll
    for (int i = 0; i < BCH; i++) {
      int chunk = i * 256 + t;
      int row = chunk >> 3, s = chunk & 7;
      int ss = s ^ (row & 7);
      GLOAD_LDS16(B + (size_t)(n0 + row) * K + k0 + ss * 8, &Bs[buf][chunk * 8]);
    }
  };

  auto compute = [&](int buf) {
#pragma unroll
    for (int kk = 0; kk < 64; kk += 32) {
      int sx8 = (((kk >> 3) + kq) ^ (r & 7)) * 8;   // swizzled 16B slot
      bf16x8 af[MI], bfr[NJ];
#pragma unroll
      for (int i = 0; i < MI; i++)
        af[i] = *(const bf16x8*)&As[buf][(wm * (BM / 2) + i * 16 + r) * 64 + sx8];
#pragma unroll
      for (int j = 0; j < NJ; j++)
        bfr[j] = *(const bf16x8*)&Bs[buf][(wn * (BN / 2) + j * 16 + r) * 64 + sx8];
#pragma unroll
      for (int i = 0; i < MI; i++)
#pragma unroll
        for (int j = 0; j < NJ; j++)
          acc[i][j] = __builtin_amdgcn_mfma_f32_16x16x32_bf16(af[i], bfr[j], acc[i][j], 0, 0, 0);
    }
  };

  int NT = KC >> 6;
  stage(0, kbase);
  __syncthreads();
  for (int step = 0; step < NT; step++) {
    int buf = step & 1;
    if (step + 1 < NT) stage(buf ^ 1, kbase + (step + 1) * 64);  // prefetch next
    compute(buf);
    __syncthreads();   // drains vmcnt (staged loads) + lets all waves finish reads
  }

#pragma unroll
  for (int i = 0; i < MI; i++) {
#pragma unroll
    for (int j = 0; j < NJ; j++) {
      int col = n0 + wn * (BN / 2) + j * 16 + r;
      float bv = (EPI == 4 && blockIdx.z != 0) ? 0.f : bias[col];
#pragma unroll
      for (int reg = 0; reg < 4; reg++) {
        int rowg = m0 + wm * (BM / 2) + i * 16 + kq * 4 + reg;
        float val = acc[i][j][reg] + bv;
        if (EPI == 0) {
          Cf[(size_t)rowg * N + col] = val;
        } else if (EPI == 1) {
          Cf[(size_t)rowg * N + col] += val;
        } else if (EPI == 2) {
          // gelu(x) = 0.5x(1+tanh z) = x / (1 + exp(-2z)), z = 0.79788456(x+0.044715x^3)
          float z2 = -1.5957691216057308f * fmaf(0.044715f * val, val * val, val);
          float gg = val / (1.f + __expf(z2));
          Cb[(size_t)rowg * N + col] = f2bf(gg);
        } else if (EPI == 3) {
          Cb[(size_t)rowg * N + col] = f2bf(val);
        } else {
          atomicAdd(&Cf[(size_t)rowg * N + col], val);
        }
      }
    }
  }
}

// ---------------- RoPE + pack q,k into (NH, L, HDP) bf16, q scaled ----------------
__global__ __launch_bounds__(256) void rope_pack(const u16* __restrict__ qkv,
                                                 const float* __restrict__ rpe,
                                                 u16* __restrict__ qp,
                                                 u16* __restrict__ kp) {
  int l = blockIdx.x;
  int t = threadIdx.x;
  __shared__ float cs[40], sn[40];
  if (t < 40) {
    float a = rpe[l * 40 + t];
    cs[t] = cosf(a);
    sn[t] = sinf(a);
  }
  __syncthreads();
  const u16* row = qkv + (size_t)l * (3 * DMODEL);
  const float scale = 0.11180339887498949f;  // 1/sqrt(80)
#pragma unroll
  for (int i = 0; i < 5; i++) {
    int e = t + i * 256;
    int h = e / HDIM, d = e - h * HDIM;
    int dm = (d < 40) ? d : d - 40;
    float c = cs[dm], s = sn[dm];
    float qv = bf2f(row[h * HDIM + d]);
    float qr = (d < 40) ? -bf2f(row[h * HDIM + d + 40]) : bf2f(row[h * HDIM + d - 40]);
    qp[((size_t)h * LTOK + l) * HDP + d] = f2bf((qv * c + qr * s) * scale);
    float kv = bf2f(row[DMODEL + h * HDIM + d]);
    float kr = (d < 40) ? -bf2f(row[DMODEL + h * HDIM + d + 40]) : bf2f(row[DMODEL + h * HDIM + d - 40]);
    kp[((size_t)h * LTOK + l) * HDP + d] = f2bf(kv * c + kr * s);
  }
  // zero the pad [80,96)
  {
    int h = t >> 4, p = t & 15;
    qp[((size_t)h * LTOK + l) * HDP + HDIM + p] = 0;
    kp[((size_t)h * LTOK + l) * HDP + HDIM + p] = 0;
  }
}

// ---------------- V transpose: (L, NH, HD) bf16 slice of qkv -> (NH, HD, L) bf16 ----------------
__global__ __launch_bounds__(256) void vtrans(const u16* __restrict__ qkv,
                                              u16* __restrict__ vt) {
  int blk = blockIdx.x;
  int h = blk >> 5, lt = blk & 31;
  int t = threadIdx.x;
  __shared__ u16 ld[64][81];
#pragma unroll
  for (int i = 0; i < 20; i++) {
    int idx = t + i * 256;
    int ll = idx / HDIM, d = idx - ll * HDIM;
    ld[ll][d] = qkv[(size_t)(lt * 64 + ll) * (3 * DMODEL) + 2 * DMODEL + h * HDIM + d];
  }
  __syncthreads();
#pragma unroll
  for (int i = 0; i < 20; i++) {
    int idx = t + i * 256;
    int d = idx >> 6, ll = idx & 63;
    vt[((size_t)h * HDIM + d) * LTOK + lt * 64 + ll] = ld[ll][d];
  }
}

// ---------------- Attention: per (head, seg, 64-row q-tile) ----------------
__global__ __launch_bounds__(256) void attn(const u16* __restrict__ qp,
                                            const u16* __restrict__ kp,
                                            const u16* __restrict__ vt,
                                            u16* __restrict__ out) {
  int bid = blockIdx.x;               // h*32 + seg*8 + qt
  int h = bid >> 5;
  int seg = (bid >> 3) & 3;
  int qt = bid & 7;
  int t = threadIdx.x, w = t >> 6, lane = t & 63;
  int r = lane & 15, kq = lane >> 4;
  __shared__ u16 P[4][16][512];
  int seg0 = seg * SEGLEN;
  int q0 = seg0 + qt * 64 + w * 16;

  // Q fragments (16 rows x 96 k, 3 k-steps)
  bf16x8 qf[3];
  const u16* qrow = qp + ((size_t)h * LTOK + q0 + r) * HDP;
#pragma unroll
  for (int kk = 0; kk < 3; kk++) qf[kk] = *(const bf16x8*)(qrow + kk * 32 + kq * 8);

  // QK^T : 32 n-fragments of 16 cols, scores in registers
  f32x4 sc[32];
#pragma unroll
  for (int j = 0; j < 32; j++) {
    f32x4 a = {0.f, 0.f, 0.f, 0.f};
    const u16* krow = kp + ((size_t)h * LTOK + seg0 + j * 16 + r) * HDP;
#pragma unroll
    for (int kk = 0; kk < 3; kk++) {
      bf16x8 bfr = *(const bf16x8*)(krow + kk * 32 + kq * 8);
      a = __builtin_amdgcn_mfma_f32_16x16x32_bf16(qf[kk], bfr, a, 0, 0, 0);
    }
    sc[j] = a;
  }

  // full-row softmax: row = kq*4 + rr lives across the 16 lanes sharing kq
#pragma unroll
  for (int rr = 0; rr < 4; rr++) {
    float m = -1e30f;
#pragma unroll
    for (int j = 0; j < 32; j++) m = fmaxf(m, sc[j][rr]);
#pragma unroll
    for (int off = 1; off < 16; off <<= 1) m = fmaxf(m, __shfl_xor(m, off));
    float s = 0.f;
#pragma unroll
    for (int j = 0; j < 32; j++) { float e = __expf(sc[j][rr] - m); sc[j][rr] = e; s += e; }
#pragma unroll
    for (int off = 1; off < 16; off <<= 1) s += __shfl_xor(s, off);
    float inv = 1.f / s;
#pragma unroll
    for (int j = 0; j < 32; j++)
      P[w][kq * 4 + rr][j * 16 + r] = f2bf(sc[j][rr] * inv);
  }
  __syncthreads();

  // PV: O(16x80) = P(16x512) @ V(512x80), V as vt (NH, HD, L)
  f32x4 oc[5] = {};
#pragma unroll
  for (int tt = 0; tt < 16; tt++) {
    bf16x8 a = *(const bf16x8*)&P[w][r][tt * 32 + kq * 8];
#pragma unroll
    for (int n = 0; n < 5; n++) {
      const u16* vrow = vt + ((size_t)h * HDIM + n * 16 + r) * LTOK + seg0 + tt * 32 + kq * 8;
      bf16x8 bfr = *(const bf16x8*)vrow;
      oc[n] = __builtin_amdgcn_mfma_f32_16x16x32_bf16(a, bfr, oc[n], 0, 0, 0);
    }
  }
#pragma unroll
  for (int n = 0; n < 5; n++)
#pragma unroll
    for (int reg = 0; reg < 4; reg++) {
      int l = q0 + kq * 4 + reg;
      out[(size_t)l * DMODEL + h * HDIM + n * 16 + r] = f2bf(oc[n][reg]);
    }
}

// ---------------- host launch ----------------
extern "C" void kernel_launch(void* const* d_in, const int* in_sizes, int n_in,
                              void* d_out, int out_size, void* d_ws, size_t ws_size,
                              hipStream_t stream) {
  (void)in_sizes; (void)n_in; (void)out_size; (void)ws_size;
  const float* x_in   = (const float*)d_in[0];
  const float* rpe    = (const float*)d_in[1];
  const float* ln1_g  = (const float*)d_in[3];
  const float* ln1_b  = (const float*)d_in[4];
  const float* ln2_g  = (const float*)d_in[5];
  const float* ln2_b  = (const float*)d_in[6];
  const float* qkv_w  = (const float*)d_in[7];
  const float* qkv_b  = (const float*)d_in[8];
  const float* proj_w = (const float*)d_in[9];
  const float* proj_b = (const float*)d_in[10];
  const float* mlp_w1 = (const float*)d_in[11];
  const float* mlp_b1 = (const float*)d_in[12];
  const float* mlp_w2 = (const float*)d_in[13];
  const float* mlp_b2 = (const float*)d_in[14];
  float* x = (float*)d_out;

  char* ws = (char*)d_ws;
  size_t off = 0;
  auto alloc = [&](size_t bytes) -> char* {
    char* p = ws + off;
    off = (off + bytes + 255) & ~(size_t)255;
    return p;
  };
  u16* wq  = (u16*)alloc((size_t)3 * DMODEL * DMODEL * 2);  // 3840x1280 bf16
  u16* wp  = (u16*)alloc((size_t)DMODEL * DMODEL * 2);      // 1280x1280
  u16* w1  = (u16*)alloc((size_t)MLPD * DMODEL * 2);        // 5120x1280
  u16* w2  = (u16*)alloc((size_t)DMODEL * MLPD * 2);        // 1280x5120
  u16* hb  = (u16*)alloc((size_t)LTOK * DMODEL * 2);        // LN out bf16
  u16* qkvb = (u16*)alloc((size_t)LTOK * 3 * DMODEL * 2);   // QKV out bf16
  u16* qp  = (u16*)alloc((size_t)NHEAD * LTOK * HDP * 2);
  u16* kp  = (u16*)alloc((size_t)NHEAD * LTOK * HDP * 2);
  u16* vt  = (u16*)alloc((size_t)NHEAD * HDIM * LTOK * 2);
  u16* att = (u16*)alloc((size_t)LTOK * DMODEL * 2);
  u16* ge  = (u16*)alloc((size_t)LTOK * MLPD * 2);

  // residual stream lives in d_out (fp32)
  hipMemcpyAsync(x, x_in, (size_t)LTOK * DMODEL * sizeof(float),
                 hipMemcpyDeviceToDevice, stream);

  for (int l = 0; l < NLAY; l++) {
    // per-layer weight conversion to bf16 (one kernel for all 4 matrices)
    cvt4<<<(C3 + 255) / 256, 256, 0, stream>>>(
        qkv_w + (size_t)l * 3 * DMODEL * DMODEL, proj_w + (size_t)l * DMODEL * DMODEL,
        mlp_w1 + (size_t)l * MLPD * DMODEL, mlp_w2 + (size_t)l * DMODEL * MLPD,
        wq, wp, w1, w2);

    // LN1 -> h (bf16)
    ln_bf16<<<LTOK, 256, 0, stream>>>(x, ln1_g + l * DMODEL, ln1_b + l * DMODEL, hb);
    // QKV = h @ Wqkv^T + b (bf16 out), 64x64 tiles -> 1920 blocks, 5/CU
    gemm_bt<3, 64, 64><<<dim3(60, 32, 1), 256, 0, stream>>>(
        hb, wq, qkv_b + (size_t)l * 3 * DMODEL, nullptr, qkvb,
        LTOK, 3 * DMODEL, DMODEL, DMODEL);
    // RoPE + pack q,k ; transpose v
    rope_pack<<<LTOK, 256, 0, stream>>>(qkvb, rpe, qp, kp);
    vtrans<<<NHEAD * 32, 256, 0, stream>>>(qkvb, vt);
    // attention
    attn<<<NHEAD * 4 * 8, 256, 0, stream>>>(qp, kp, vt, att);
    // x += att @ Wproj^T + b   (split-K=2 -> 1280 blocks)
    gemm_bt<4, 64, 64><<<dim3(20, 32, 2), 256, 0, stream>>>(
        att, wp, proj_b + (size_t)l * DMODEL, x, nullptr,
        LTOK, DMODEL, DMODEL, DMODEL / 2);
    // LN2 -> h
    ln_bf16<<<LTOK, 256, 0, stream>>>(x, ln2_g + l * DMODEL, ln2_b + l * DMODEL, hb);
    // ge = gelu(h @ W1^T + b1) (bf16 out), 64x64 tiles -> 2560 blocks
    gemm_bt<2, 64, 64><<<dim3(80, 32, 1), 256, 0, stream>>>(
        hb, w1, mlp_b1 + (size_t)l * MLPD, nullptr, ge,
        LTOK, MLPD, DMODEL, DMODEL);
    // x += ge @ W2^T + b2   (split-K=4 -> 2560 blocks)
    gemm_bt<4, 64, 64><<<dim3(20, 32, 4), 256, 0, stream>>>(
        ge, w2, mlp_b2 + (size_t)l * DMODEL, x, nullptr,
        LTOK, DMODEL, MLPD, MLPD / 4);
  }
}

// Round 7
// 1019.110 us; speedup vs baseline: 1.0605x; 1.0605x over previous
//
#include <hip/hip_runtime.h>
#include <cstdint>
#include <cstddef>

typedef unsigned short u16;
typedef __bf16 bf16_t;
typedef bf16_t bf16x8 __attribute__((ext_vector_type(8)));
typedef float f32x4 __attribute__((ext_vector_type(4)));

#define NLAY 4
#define DMODEL 1280
#define NHEAD 16
#define HDIM 80
#define HDP 96           // padded head dim for QK^T K-loop (3 x 32)
#define MLPD 5120
#define LTOK 2048
#define SEGLEN 512

__device__ __forceinline__ u16 f2bf(float f) {
  union { float f; unsigned u; } x; x.f = f;
  unsigned r = x.u + 0x7fffu + ((x.u >> 16) & 1u);
  return (u16)(r >> 16);
}
__device__ __forceinline__ float bf2f(u16 s) {
  union { unsigned u; float f; } x; x.u = ((unsigned)s) << 16;
  return x.f;
}

#define GLOAD_LDS16(gsrc, ldst) \
  __builtin_amdgcn_global_load_lds((const __attribute__((address_space(1))) void*)(gsrc), \
                                   (__attribute__((address_space(3))) void*)(ldst), 16, 0, 0)

__device__ __forceinline__ void barrier_mem() {
  asm volatile("s_barrier" ::: "memory");
}

// ---------------- all-weights fp32 -> bf16 convert (one layer, one kernel) ----------------
#define C0 (3 * DMODEL * DMODEL / 4)          // qkv_w float4s
#define C1 (C0 + DMODEL * DMODEL / 4)         // + proj_w
#define C2 (C1 + MLPD * DMODEL / 4)           // + mlp_w1
#define C3 (C2 + DMODEL * MLPD / 4)           // + mlp_w2
__global__ __launch_bounds__(256) void cvt4(const float* __restrict__ s_q,
                                            const float* __restrict__ s_p,
                                            const float* __restrict__ s_1,
                                            const float* __restrict__ s_2,
                                            u16* __restrict__ o_q, u16* __restrict__ o_p,
                                            u16* __restrict__ o_1, u16* __restrict__ o_2) {
  int i = blockIdx.x * 256 + threadIdx.x;
  const float* src; u16* dst; int off;
  if (i < C0)      { src = s_q; dst = o_q; off = i; }
  else if (i < C1) { src = s_p; dst = o_p; off = i - C0; }
  else if (i < C2) { src = s_1; dst = o_1; off = i - C1; }
  else if (i < C3) { src = s_2; dst = o_2; off = i - C2; }
  else return;
  const float4 v = reinterpret_cast<const float4*>(src)[off];
  union { u16 s[4]; uint2 u; } o;
  o.s[0] = f2bf(v.x); o.s[1] = f2bf(v.y); o.s[2] = f2bf(v.z); o.s[3] = f2bf(v.w);
  reinterpret_cast<uint2*>(dst)[off] = o.u;
}

// ---------------- LayerNorm (fp32 in, bf16 out) ----------------
__global__ __launch_bounds__(256) void ln_bf16(const float* __restrict__ x,
                                               const float* __restrict__ g,
                                               const float* __restrict__ b,
                                               u16* __restrict__ out) {
  int row = blockIdx.x;
  int t = threadIdx.x;
  const float* xr = x + (size_t)row * DMODEL;
  float v[5]; float s = 0.f, s2 = 0.f;
#pragma unroll
  for (int i = 0; i < 5; i++) { v[i] = xr[t + i * 256]; s += v[i]; s2 += v[i] * v[i]; }
#pragma unroll
  for (int off = 32; off; off >>= 1) { s += __shfl_down(s, off); s2 += __shfl_down(s2, off); }
  __shared__ float ps[4], ps2[4];
  int w = t >> 6;
  if ((t & 63) == 0) { ps[w] = s; ps2[w] = s2; }
  __syncthreads();
  s = ps[0] + ps[1] + ps[2] + ps[3];
  s2 = ps2[0] + ps2[1] + ps2[2] + ps2[3];
  float mean = s * (1.f / DMODEL);
  float var = s2 * (1.f / DMODEL) - mean * mean;
  float inv = rsqrtf(var + 1e-6f);
#pragma unroll
  for (int i = 0; i < 5; i++) {
    int c = t + i * 256;
    out[(size_t)row * DMODEL + c] = f2bf((v[i] - mean) * inv * g[c] + b[c]);
  }
}

// ---------------- deep-pipelined GEMM: 256Mx128N, BK=64, 8 waves, 3-buf counted vmcnt ----
// C[M,N] = A[M,K](bf16) @ B[N,K](bf16)^T + bias.
// Schedule per K-tile (4 phases, snake quadrant order):
//   p0: vmcnt(6)+barrier; read A0,B0 frags; stage(t+2, A-half0); MFMA q(0,0); barrier
//   p1:                    read B1 frags;   stage(t+2, A-half1); MFMA q(0,1); barrier
//   p2:                    read A1 frags;   stage(t+2, B);       MFMA q(1,1); barrier
//   p3:                    read B0 frags;                        MFMA q(1,0)
// 3 buffers: tile t+2 stages into buf[(t+2)%3] = buf[(t-1)%3], whose readers all
// finished before this tile's p0 barrier -> race-free. vmcnt(6) leaves exactly
// tile t+1's 6 loads in flight (in-order retirement => tile t landed).
// EPI 2: Cb = gelu(val + bias)  (bf16); EPI 3: Cb = val + bias (bf16)
template <int EPI>
__global__ __launch_bounds__(512) void gemm8(const u16* __restrict__ A,
                                             const u16* __restrict__ B,
                                             const float* __restrict__ bias,
                                             u16* __restrict__ Cb,
                                             int M, int N, int K) {
  __shared__ u16 As[3][256 * 64];   // 96 KB
  __shared__ u16 Bs[3][128 * 64];   // 48 KB

  int gN = gridDim.x, gM = gridDim.y;
  int flat = blockIdx.x + gN * blockIdx.y;
  int nwg = gN * gM;
  int qc = nwg >> 3, rc = nwg & 7;
  int xcd = flat & 7, pos = flat >> 3;
  int start = (xcd < rc) ? xcd * (qc + 1) : rc * (qc + 1) + (xcd - rc) * qc;
  int swz = start + pos;
  int m0 = (swz % gM) * 256;
  int n0 = (swz / gM) * 128;

  int t = threadIdx.x, lane = t & 63, w = t >> 6;
  int wm = w >> 1, wn = w & 1;            // 4M x 2N waves, wave tile 64x64
  int r = lane & 15, kq = lane >> 4;
  f32x4 acc[4][4] = {};

  auto stageA = [&](int buf, int k0, int half) {
#pragma unroll
    for (int i = 0; i < 2; i++) {
      int chunk = half * 1024 + i * 512 + t;
      int row = chunk >> 3, s = chunk & 7;
      int ss = s ^ (row & 7);
      GLOAD_LDS16(A + (size_t)(m0 + row) * K + k0 + ss * 8, &As[buf][chunk * 8]);
    }
  };
  auto stageB = [&](int buf, int k0) {
#pragma unroll
    for (int i = 0; i < 2; i++) {
      int chunk = i * 512 + t;
      int row = chunk >> 3, s = chunk & 7;
      int ss = s ^ (row & 7);
      GLOAD_LDS16(B + (size_t)(n0 + row) * K + k0 + ss * 8, &Bs[buf][chunk * 8]);
    }
  };

  bf16x8 af[2][2], bf[2][2];
  auto loadA = [&](const u16* as, int mh) {
#pragma unroll
    for (int i2 = 0; i2 < 2; i2++)
#pragma unroll
      for (int ks = 0; ks < 2; ks++) {
        int row = wm * 64 + (2 * mh + i2) * 16 + r;
        int sx8 = (ks * 4 + kq) ^ (r & 7);
        af[i2][ks] = *(const bf16x8*)&as[row * 64 + sx8 * 8];
      }
  };
  auto loadB = [&](const u16* bs, int nh) {
#pragma unroll
    for (int j2 = 0; j2 < 2; j2++)
#pragma unroll
      for (int ks = 0; ks < 2; ks++) {
        int row = wn * 64 + (2 * nh + j2) * 16 + r;
        int sx8 = (ks * 4 + kq) ^ (r & 7);
        bf[j2][ks] = *(const bf16x8*)&bs[row * 64 + sx8 * 8];
      }
  };
  auto mfma8 = [&](int mh, int nh) {
    __builtin_amdgcn_s_setprio(1);
#pragma unroll
    for (int i2 = 0; i2 < 2; i2++)
#pragma unroll
      for (int j2 = 0; j2 < 2; j2++)
#pragma unroll
        for (int ks = 0; ks < 2; ks++)
          acc[2 * mh + i2][2 * nh + j2] = __builtin_amdgcn_mfma_f32_16x16x32_bf16(
              af[i2][ks], bf[j2][ks], acc[2 * mh + i2][2 * nh + j2], 0, 0, 0);
    __builtin_amdgcn_s_setprio(0);
  };

  int NT = K >> 6;
  // prologue: tiles 0 and 1 fully staged (12 loads in flight)
  stageA(0, 0, 0); stageA(0, 0, 1); stageB(0, 0);
  stageA(1, 64, 0); stageA(1, 64, 1); stageB(1, 64);

  int bt = 0;
  for (int kt = 0; kt < NT; kt++) {
    if (kt == NT - 1) asm volatile("s_waitcnt vmcnt(0)" ::: "memory");
    else              asm volatile("s_waitcnt vmcnt(6)" ::: "memory");
    barrier_mem();                       // all waves' tile-kt loads landed chip-wide
    const u16* as = As[bt];
    const u16* bs = Bs[bt];
    int b2 = bt + 2; if (b2 >= 3) b2 -= 3;
    int k2 = (kt + 2) << 6;
    bool st = (kt + 2) < NT;
    // p0: quadrant (0,0)
    loadA(as, 0); loadB(bs, 0);
    if (st) stageA(b2, k2, 0);
    mfma8(0, 0);
    barrier_mem();
    // p1: quadrant (0,1)
    loadB(bs, 1);
    if (st) stageA(b2, k2, 1);
    mfma8(0, 1);
    barrier_mem();
    // p2: quadrant (1,1)
    loadA(as, 1);
    if (st) stageB(b2, k2);
    mfma8(1, 1);
    barrier_mem();
    // p3: quadrant (1,0)
    loadB(bs, 0);
    mfma8(1, 0);
    bt++; if (bt == 3) bt = 0;
  }

#pragma unroll
  for (int i = 0; i < 4; i++) {
#pragma unroll
    for (int j = 0; j < 4; j++) {
      int col = n0 + wn * 64 + j * 16 + r;
      float bv = bias[col];
#pragma unroll
      for (int reg = 0; reg < 4; reg++) {
        int rowg = m0 + wm * 64 + i * 16 + kq * 4 + reg;
        float val = acc[i][j][reg] + bv;
        if (EPI == 2) {
          float z2 = -1.5957691216057308f * fmaf(0.044715f * val, val * val, val);
          float gg = val / (1.f + __expf(z2));
          Cb[(size_t)rowg * N + col] = f2bf(gg);
        } else {
          Cb[(size_t)rowg * N + col] = f2bf(val);
        }
      }
    }
  }
}

// ---------------- GEMM: C[M,N] = A[M,K](bf16) @ B[N,K](bf16)^T + bias ----------------
// Round-3-proven 2-phase prefetch double-buffer, 4 waves, BK=64, zero-conflict swizzle.
// EPI 1: Cf += val + bias (residual accumulate, fp32)
template <int EPI, int BM, int BN>
__global__ __launch_bounds__(256) void gemm_bt(const u16* __restrict__ A,
                                               const u16* __restrict__ B,
                                               const float* __restrict__ bias,
                                               float* __restrict__ Cf,
                                               u16* __restrict__ Cb,
                                               int M, int N, int K) {
  constexpr int MI = BM / 32;
  constexpr int NJ = BN / 32;
  constexpr int ACH = BM * 64 / (256 * 8);
  constexpr int BCH = BN * 64 / (256 * 8);
  __shared__ u16 As[2][BM * 64];
  __shared__ u16 Bs[2][BN * 64];

  int gN = gridDim.x, gM = gridDim.y;
  int flat = blockIdx.x + gN * blockIdx.y;
  int nwg = gN * gM;
  int qc = nwg >> 3, rc = nwg & 7;
  int xcd = flat & 7, pos = flat >> 3;
  int start = (xcd < rc) ? xcd * (qc + 1) : rc * (qc + 1) + (xcd - rc) * qc;
  int swz = start + pos;
  int m0 = (swz % gM) * BM;
  int n0 = (swz / gM) * BN;

  int t = threadIdx.x, lane = t & 63, w = t >> 6;
  int wm = w >> 1, wn = w & 1;
  int r = lane & 15, kq = lane >> 4;
  f32x4 acc[MI][NJ] = {};

  auto stage = [&](int buf, int k0) {
#pragma unroll
    for (int i = 0; i < ACH; i++) {
      int chunk = i * 256 + t;
      int row = chunk >> 3, s = chunk & 7;
      int ss = s ^ (row & 7);
      GLOAD_LDS16(A + (size_t)(m0 + row) * K + k0 + ss * 8, &As[buf][chunk * 8]);
    }
#pragma unroll
    for (int i = 0; i < BCH; i++) {
      int chunk = i * 256 + t;
      int row = chunk >> 3, s = chunk & 7;
      int ss = s ^ (row & 7);
      GLOAD_LDS16(B + (size_t)(n0 + row) * K + k0 + ss * 8, &Bs[buf][chunk * 8]);
    }
  };

  auto compute = [&](int buf) {
#pragma unroll
    for (int kk = 0; kk < 64; kk += 32) {
      int sx8 = (((kk >> 3) + kq) ^ (r & 7)) * 8;
      bf16x8 af[MI], bfr[NJ];
#pragma unroll
      for (int i = 0; i < MI; i++)
        af[i] = *(const bf16x8*)&As[buf][(wm * (BM / 2) + i * 16 + r) * 64 + sx8];
#pragma unroll
      for (int j = 0; j < NJ; j++)
        bfr[j] = *(const bf16x8*)&Bs[buf][(wn * (BN / 2) + j * 16 + r) * 64 + sx8];
#pragma unroll
      for (int i = 0; i < MI; i++)
#pragma unroll
        for (int j = 0; j < NJ; j++)
          acc[i][j] = __builtin_amdgcn_mfma_f32_16x16x32_bf16(af[i], bfr[j], acc[i][j], 0, 0, 0);
    }
  };

  int NT = K >> 6;
  stage(0, 0);
  __syncthreads();
  for (int step = 0; step < NT; step++) {
    int buf = step & 1;
    if (step + 1 < NT) stage(buf ^ 1, (step + 1) * 64);
    compute(buf);
    __syncthreads();
  }

#pragma unroll
  for (int i = 0; i < MI; i++) {
#pragma unroll
    for (int j = 0; j < NJ; j++) {
      int col = n0 + wn * (BN / 2) + j * 16 + r;
      float bv = bias[col];
#pragma unroll
      for (int reg = 0; reg < 4; reg++) {
        int rowg = m0 + wm * (BM / 2) + i * 16 + kq * 4 + reg;
        float val = acc[i][j][reg] + bv;
        if (EPI == 1) {
          Cf[(size_t)rowg * N + col] += val;
        } else {
          Cb[(size_t)rowg * N + col] = f2bf(val);
        }
      }
    }
  }
}

// ---------------- RoPE + pack q,k into (NH, L, HDP) bf16, q scaled ----------------
__global__ __launch_bounds__(256) void rope_pack(const u16* __restrict__ qkv,
                                                 const float* __restrict__ rpe,
                                                 u16* __restrict__ qp,
                                                 u16* __restrict__ kp) {
  int l = blockIdx.x;
  int t = threadIdx.x;
  __shared__ float cs[40], sn[40];
  if (t < 40) {
    float a = rpe[l * 40 + t];
    cs[t] = cosf(a);
    sn[t] = sinf(a);
  }
  __syncthreads();
  const u16* row = qkv + (size_t)l * (3 * DMODEL);
  const float scale = 0.11180339887498949f;  // 1/sqrt(80)
#pragma unroll
  for (int i = 0; i < 5; i++) {
    int e = t + i * 256;
    int h = e / HDIM, d = e - h * HDIM;
    int dm = (d < 40) ? d : d - 40;
    float c = cs[dm], s = sn[dm];
    float qv = bf2f(row[h * HDIM + d]);
    float qr = (d < 40) ? -bf2f(row[h * HDIM + d + 40]) : bf2f(row[h * HDIM + d - 40]);
    qp[((size_t)h * LTOK + l) * HDP + d] = f2bf((qv * c + qr * s) * scale);
    float kv = bf2f(row[DMODEL + h * HDIM + d]);
    float kr = (d < 40) ? -bf2f(row[DMODEL + h * HDIM + d + 40]) : bf2f(row[DMODEL + h * HDIM + d - 40]);
    kp[((size_t)h * LTOK + l) * HDP + d] = f2bf(kv * c + kr * s);
  }
  // zero the pad [80,96)
  {
    int h = t >> 4, p = t & 15;
    qp[((size_t)h * LTOK + l) * HDP + HDIM + p] = 0;
    kp[((size_t)h * LTOK + l) * HDP + HDIM + p] = 0;
  }
}

// ---------------- V transpose: (L, NH, HD) bf16 slice of qkv -> (NH, HD, L) bf16 ----------------
__global__ __launch_bounds__(256) void vtrans(const u16* __restrict__ qkv,
                                              u16* __restrict__ vt) {
  int blk = blockIdx.x;
  int h = blk >> 5, lt = blk & 31;
  int t = threadIdx.x;
  __shared__ u16 ld[64][81];
#pragma unroll
  for (int i = 0; i < 20; i++) {
    int idx = t + i * 256;
    int ll = idx / HDIM, d = idx - ll * HDIM;
    ld[ll][d] = qkv[(size_t)(lt * 64 + ll) * (3 * DMODEL) + 2 * DMODEL + h * HDIM + d];
  }
  __syncthreads();
#pragma unroll
  for (int i = 0; i < 20; i++) {
    int idx = t + i * 256;
    int d = idx >> 6, ll = idx & 63;
    vt[((size_t)h * HDIM + d) * LTOK + lt * 64 + ll] = ld[ll][d];
  }
}

// ---------------- Attention: per (head, seg, 64-row q-tile) ----------------
__global__ __launch_bounds__(256) void attn(const u16* __restrict__ qp,
                                            const u16* __restrict__ kp,
                                            const u16* __restrict__ vt,
                                            u16* __restrict__ out) {
  int bid = blockIdx.x;               // h*32 + seg*8 + qt
  int h = bid >> 5;
  int seg = (bid >> 3) & 3;
  int qt = bid & 7;
  int t = threadIdx.x, w = t >> 6, lane = t & 63;
  int r = lane & 15, kq = lane >> 4;
  __shared__ u16 P[4][16][512];
  int seg0 = seg * SEGLEN;
  int q0 = seg0 + qt * 64 + w * 16;

  bf16x8 qf[3];
  const u16* qrow = qp + ((size_t)h * LTOK + q0 + r) * HDP;
#pragma unroll
  for (int kk = 0; kk < 3; kk++) qf[kk] = *(const bf16x8*)(qrow + kk * 32 + kq * 8);

  f32x4 sc[32];
#pragma unroll
  for (int j = 0; j < 32; j++) {
    f32x4 a = {0.f, 0.f, 0.f, 0.f};
    const u16* krow = kp + ((size_t)h * LTOK + seg0 + j * 16 + r) * HDP;
#pragma unroll
    for (int kk = 0; kk < 3; kk++) {
      bf16x8 bfr = *(const bf16x8*)(krow + kk * 32 + kq * 8);
      a = __builtin_amdgcn_mfma_f32_16x16x32_bf16(qf[kk], bfr, a, 0, 0, 0);
    }
    sc[j] = a;
  }

#pragma unroll
  for (int rr = 0; rr < 4; rr++) {
    float m = -1e30f;
#pragma unroll
    for (int j = 0; j < 32; j++) m = fmaxf(m, sc[j][rr]);
#pragma unroll
    for (int off = 1; off < 16; off <<= 1) m = fmaxf(m, __shfl_xor(m, off));
    float s = 0.f;
#pragma unroll
    for (int j = 0; j < 32; j++) { float e = __expf(sc[j][rr] - m); sc[j][rr] = e; s += e; }
#pragma unroll
    for (int off = 1; off < 16; off <<= 1) s += __shfl_xor(s, off);
    float inv = 1.f / s;
#pragma unroll
    for (int j = 0; j < 32; j++)
      P[w][kq * 4 + rr][j * 16 + r] = f2bf(sc[j][rr] * inv);
  }
  __syncthreads();

  f32x4 oc[5] = {};
#pragma unroll
  for (int tt = 0; tt < 16; tt++) {
    bf16x8 a = *(const bf16x8*)&P[w][r][tt * 32 + kq * 8];
#pragma unroll
    for (int n = 0; n < 5; n++) {
      const u16* vrow = vt + ((size_t)h * HDIM + n * 16 + r) * LTOK + seg0 + tt * 32 + kq * 8;
      bf16x8 bfr = *(const bf16x8*)vrow;
      oc[n] = __builtin_amdgcn_mfma_f32_16x16x32_bf16(a, bfr, oc[n], 0, 0, 0);
    }
  }
#pragma unroll
  for (int n = 0; n < 5; n++)
#pragma unroll
    for (int reg = 0; reg < 4; reg++) {
      int l = q0 + kq * 4 + reg;
      out[(size_t)l * DMODEL + h * HDIM + n * 16 + r] = f2bf(oc[n][reg]);
    }
}

// ---------------- host launch ----------------
extern "C" void kernel_launch(void* const* d_in, const int* in_sizes, int n_in,
                              void* d_out, int out_size, void* d_ws, size_t ws_size,
                              hipStream_t stream) {
  (void)in_sizes; (void)n_in; (void)out_size; (void)ws_size;
  const float* x_in   = (const float*)d_in[0];
  const float* rpe    = (const float*)d_in[1];
  const float* ln1_g  = (const float*)d_in[3];
  const float* ln1_b  = (const float*)d_in[4];
  const float* ln2_g  = (const float*)d_in[5];
  const float* ln2_b  = (const float*)d_in[6];
  const float* qkv_w  = (const float*)d_in[7];
  const float* qkv_b  = (const float*)d_in[8];
  const float* proj_w = (const float*)d_in[9];
  const float* proj_b = (const float*)d_in[10];
  const float* mlp_w1 = (const float*)d_in[11];
  const float* mlp_b1 = (const float*)d_in[12];
  const float* mlp_w2 = (const float*)d_in[13];
  const float* mlp_b2 = (const float*)d_in[14];
  float* x = (float*)d_out;

  char* ws = (char*)d_ws;
  size_t off = 0;
  auto alloc = [&](size_t bytes) -> char* {
    char* p = ws + off;
    off = (off + bytes + 255) & ~(size_t)255;
    return p;
  };
  u16* wq  = (u16*)alloc((size_t)3 * DMODEL * DMODEL * 2);
  u16* wp  = (u16*)alloc((size_t)DMODEL * DMODEL * 2);
  u16* w1  = (u16*)alloc((size_t)MLPD * DMODEL * 2);
  u16* w2  = (u16*)alloc((size_t)DMODEL * MLPD * 2);
  u16* hb  = (u16*)alloc((size_t)LTOK * DMODEL * 2);
  u16* qkvb = (u16*)alloc((size_t)LTOK * 3 * DMODEL * 2);
  u16* qp  = (u16*)alloc((size_t)NHEAD * LTOK * HDP * 2);
  u16* kp  = (u16*)alloc((size_t)NHEAD * LTOK * HDP * 2);
  u16* vt  = (u16*)alloc((size_t)NHEAD * HDIM * LTOK * 2);
  u16* att = (u16*)alloc((size_t)LTOK * DMODEL * 2);
  u16* ge  = (u16*)alloc((size_t)LTOK * MLPD * 2);

  hipMemcpyAsync(x, x_in, (size_t)LTOK * DMODEL * sizeof(float),
                 hipMemcpyDeviceToDevice, stream);

  for (int l = 0; l < NLAY; l++) {
    cvt4<<<(C3 + 255) / 256, 256, 0, stream>>>(
        qkv_w + (size_t)l * 3 * DMODEL * DMODEL, proj_w + (size_t)l * DMODEL * DMODEL,
        mlp_w1 + (size_t)l * MLPD * DMODEL, mlp_w2 + (size_t)l * DMODEL * MLPD,
        wq, wp, w1, w2);

    // LN1 -> h (bf16)
    ln_bf16<<<LTOK, 256, 0, stream>>>(x, ln1_g + l * DMODEL, ln1_b + l * DMODEL, hb);
    // QKV = h @ Wqkv^T + b (bf16 out): 256x128 deep-pipelined, grid 30x8 = 240 blocks
    gemm8<3><<<dim3(30, 8), 512, 0, stream>>>(
        hb, wq, qkv_b + (size_t)l * 3 * DMODEL, qkvb, LTOK, 3 * DMODEL, DMODEL);
    // RoPE + pack q,k ; transpose v
    rope_pack<<<LTOK, 256, 0, stream>>>(qkvb, rpe, qp, kp);
    vtrans<<<NHEAD * 32, 256, 0, stream>>>(qkvb, vt);
    // attention
    attn<<<NHEAD * 4 * 8, 256, 0, stream>>>(qp, kp, vt, att);
    // x += att @ Wproj^T + b   (64x64 2-phase, 640 blocks)
    gemm_bt<1, 64, 64><<<dim3(20, 32), 256, 0, stream>>>(
        att, wp, proj_b + (size_t)l * DMODEL, x, nullptr, LTOK, DMODEL, DMODEL);
    // LN2 -> h
    ln_bf16<<<LTOK, 256, 0, stream>>>(x, ln2_g + l * DMODEL, ln2_b + l * DMODEL, hb);
    // ge = gelu(h @ W1^T + b1): 256x128 deep-pipelined, grid 40x8 = 320 blocks
    gemm8<2><<<dim3(40, 8), 512, 0, stream>>>(
        hb, w1, mlp_b1 + (size_t)l * MLPD, ge, LTOK, MLPD, DMODEL);
    // x += ge @ W2^T + b2   (64x64 2-phase, 640 blocks)
    gemm_bt<1, 64, 64><<<dim3(20, 32), 256, 0, stream>>>(
        ge, w2, mlp_b2 + (size_t)l * DMODEL, x, nullptr, LTOK, DMODEL, MLPD);
  }
}

// Round 8
// 1002.802 us; speedup vs baseline: 1.0777x; 1.0163x over previous
//
#include <hip/hip_runtime.h>
#include <cstdint>
#include <cstddef>

typedef unsigned short u16;
typedef __bf16 bf16_t;
typedef bf16_t bf16x8 __attribute__((ext_vector_type(8)));
typedef float f32x4 __attribute__((ext_vector_type(4)));

#define NLAY 4
#define DMODEL 1280
#define NHEAD 16
#define HDIM 80
#define HDP 96           // padded head dim for QK^T K-loop (3 x 32)
#define MLPD 5120
#define LTOK 2048
#define SEGLEN 512

__device__ __forceinline__ u16 f2bf(float f) {
  union { float f; unsigned u; } x; x.f = f;
  unsigned r = x.u + 0x7fffu + ((x.u >> 16) & 1u);
  return (u16)(r >> 16);
}
__device__ __forceinline__ float bf2f(u16 s) {
  union { unsigned u; float f; } x; x.u = ((unsigned)s) << 16;
  return x.f;
}

#define GLOAD_LDS16(gsrc, ldst) \
  __builtin_amdgcn_global_load_lds((const __attribute__((address_space(1))) void*)(gsrc), \
                                   (__attribute__((address_space(3))) void*)(ldst), 16, 0, 0)

__device__ __forceinline__ void barrier_mem() {
  asm volatile("s_barrier" ::: "memory");
}

// ---------------- all-weights fp32 -> bf16 convert (one layer, one kernel) ----------------
#define C0 (3 * DMODEL * DMODEL / 4)          // qkv_w float4s
#define C1 (C0 + DMODEL * DMODEL / 4)         // + proj_w
#define C2 (C1 + MLPD * DMODEL / 4)           // + mlp_w1
#define C3 (C2 + DMODEL * MLPD / 4)           // + mlp_w2
__global__ __launch_bounds__(256) void cvt4(const float* __restrict__ s_q,
                                            const float* __restrict__ s_p,
                                            const float* __restrict__ s_1,
                                            const float* __restrict__ s_2,
                                            u16* __restrict__ o_q, u16* __restrict__ o_p,
                                            u16* __restrict__ o_1, u16* __restrict__ o_2) {
  int i = blockIdx.x * 256 + threadIdx.x;
  const float* src; u16* dst; int off;
  if (i < C0)      { src = s_q; dst = o_q; off = i; }
  else if (i < C1) { src = s_p; dst = o_p; off = i - C0; }
  else if (i < C2) { src = s_1; dst = o_1; off = i - C1; }
  else if (i < C3) { src = s_2; dst = o_2; off = i - C2; }
  else return;
  const float4 v = reinterpret_cast<const float4*>(src)[off];
  union { u16 s[4]; uint2 u; } o;
  o.s[0] = f2bf(v.x); o.s[1] = f2bf(v.y); o.s[2] = f2bf(v.z); o.s[3] = f2bf(v.w);
  reinterpret_cast<uint2*>(dst)[off] = o.u;
}

// ---------------- LayerNorm (fp32 in, bf16 out) ----------------
__global__ __launch_bounds__(256) void ln_bf16(const float* __restrict__ x,
                                               const float* __restrict__ g,
                                               const float* __restrict__ b,
                                               u16* __restrict__ out) {
  int row = blockIdx.x;
  int t = threadIdx.x;
  const float* xr = x + (size_t)row * DMODEL;
  float v[5]; float s = 0.f, s2 = 0.f;
#pragma unroll
  for (int i = 0; i < 5; i++) { v[i] = xr[t + i * 256]; s += v[i]; s2 += v[i] * v[i]; }
#pragma unroll
  for (int off = 32; off; off >>= 1) { s += __shfl_down(s, off); s2 += __shfl_down(s2, off); }
  __shared__ float ps[4], ps2[4];
  int w = t >> 6;
  if ((t & 63) == 0) { ps[w] = s; ps2[w] = s2; }
  __syncthreads();
  s = ps[0] + ps[1] + ps[2] + ps[3];
  s2 = ps2[0] + ps2[1] + ps2[2] + ps2[3];
  float mean = s * (1.f / DMODEL);
  float var = s2 * (1.f / DMODEL) - mean * mean;
  float inv = rsqrtf(var + 1e-6f);
#pragma unroll
  for (int i = 0; i < 5; i++) {
    int c = t + i * 256;
    out[(size_t)row * DMODEL + c] = f2bf((v[i] - mean) * inv * g[c] + b[c]);
  }
}

// ---------------- m201-geometry GEMM: 256x256 tile, BK=32, 8 waves, 3-buf counted vmcnt ----
// C[M,N] = A[M,K](bf16) @ B[N,K](bf16)^T + bias. Per-wave output 128x64
// (2M x 4N waves). Per K-tile: 2 phases x {ds_read || stage 2 gloads || 16 MFMA}.
// Staging runs 2 K-tiles ahead into buf[(kt+2)%3]; boundary wait vmcnt(4)
// (= tile kt+1's 4 loads, the only ones newer than tile kt's) -> tile kt
// landed for ALL waves after the barrier. Tail tiles use vmcnt(0).
// BK=32 swizzle: slot ^= (row>>1)&3 both on pre-swizzled global source and
// ds_read -> bank groups (r&1, kq^((r>>1)&3)) carry exactly 8 lanes each =
// wave64 b128 minimum, zero excess conflict.
// EPI 2: Cb = gelu(val + bias)  (bf16); EPI 3: Cb = val + bias (bf16)
template <int EPI>
__global__ __launch_bounds__(512, 2) void gemm256(const u16* __restrict__ A,
                                                  const u16* __restrict__ B,
                                                  const float* __restrict__ bias,
                                                  u16* __restrict__ Cb,
                                                  int M, int N, int K) {
  __shared__ u16 As[3][256 * 32];   // 48 KB
  __shared__ u16 Bs[3][256 * 32];   // 48 KB

  int gN = gridDim.x, gM = gridDim.y;
  int flat = blockIdx.x + gN * blockIdx.y;
  int nwg = gN * gM;
  int qc = nwg >> 3, rc = nwg & 7;
  int xcd = flat & 7, pos = flat >> 3;
  int start = (xcd < rc) ? xcd * (qc + 1) : rc * (qc + 1) + (xcd - rc) * qc;
  int swz = start + pos;
  int m0 = (swz % gM) * 256;
  int n0 = (swz / gM) * 256;

  int t = threadIdx.x, lane = t & 63, w = t >> 6;
  int wm = w >> 2, wn = w & 3;            // 2M x 4N waves, wave tile 128x64
  int r = lane & 15, kq = lane >> 4;
  f32x4 acc[8][4] = {};

  auto stageA = [&](int buf, int k0) {
#pragma unroll
    for (int i = 0; i < 2; i++) {
      int chunk = i * 512 + t;            // 1024 chunks = 256 rows x 4 slots
      int row = chunk >> 2, s = chunk & 3;
      int ss = s ^ ((row >> 1) & 3);
      GLOAD_LDS16(A + (size_t)(m0 + row) * K + k0 + ss * 8, &As[buf][chunk * 8]);
    }
  };
  auto stageB = [&](int buf, int k0) {
#pragma unroll
    for (int i = 0; i < 2; i++) {
      int chunk = i * 512 + t;
      int row = chunk >> 2, s = chunk & 3;
      int ss = s ^ ((row >> 1) & 3);
      GLOAD_LDS16(B + (size_t)(n0 + row) * K + k0 + ss * 8, &Bs[buf][chunk * 8]);
    }
  };

  int NT = K >> 5;
  // prologue: tiles 0 and 1 fully staged (8 loads in flight)
  stageA(0, 0); stageB(0, 0);
  stageA(1, 32); stageB(1, 32);

  int bt = 0;
  for (int kt = 0; kt < NT; kt++) {
    if (kt >= NT - 2) asm volatile("s_waitcnt vmcnt(0)" ::: "memory");
    else              asm volatile("s_waitcnt vmcnt(4)" ::: "memory");
    barrier_mem();                       // tile kt landed chip-wide
    const u16* as = As[bt];
    const u16* bs = Bs[bt];
    int b2 = bt + 2; if (b2 >= 3) b2 -= 3;
    bool st = (kt + 2) < NT;
    int k2 = (kt + 2) << 5;

    // p0: read all 8 A-frags + B-frags j=0,1 ; stage A(kt+2) ; 16 MFMA
    bf16x8 af[8], bfr[2];
#pragma unroll
    for (int i = 0; i < 8; i++) {
      int row = wm * 128 + i * 16 + r;
      int ss = kq ^ ((row >> 1) & 3);
      af[i] = *(const bf16x8*)&as[row * 32 + ss * 8];
    }
#pragma unroll
    for (int j = 0; j < 2; j++) {
      int row = wn * 64 + j * 16 + r;
      int ss = kq ^ ((row >> 1) & 3);
      bfr[j] = *(const bf16x8*)&bs[row * 32 + ss * 8];
    }
    if (st) stageA(b2, k2);
    __builtin_amdgcn_s_setprio(1);
#pragma unroll
    for (int i = 0; i < 8; i++)
#pragma unroll
      for (int j = 0; j < 2; j++)
        acc[i][j] = __builtin_amdgcn_mfma_f32_16x16x32_bf16(af[i], bfr[j], acc[i][j], 0, 0, 0);
    __builtin_amdgcn_s_setprio(0);
    barrier_mem();

    // p1: read B-frags j=2,3 ; stage B(kt+2) ; 16 MFMA
#pragma unroll
    for (int j = 0; j < 2; j++) {
      int row = wn * 64 + (j + 2) * 16 + r;
      int ss = kq ^ ((row >> 1) & 3);
      bfr[j] = *(const bf16x8*)&bs[row * 32 + ss * 8];
    }
    if (st) stageB(b2, k2);
    __builtin_amdgcn_s_setprio(1);
#pragma unroll
    for (int i = 0; i < 8; i++)
#pragma unroll
      for (int j = 0; j < 2; j++)
        acc[i][j + 2] = __builtin_amdgcn_mfma_f32_16x16x32_bf16(af[i], bfr[j], acc[i][j + 2], 0, 0, 0);
    __builtin_amdgcn_s_setprio(0);

    bt++; if (bt == 3) bt = 0;
  }

#pragma unroll
  for (int i = 0; i < 8; i++) {
#pragma unroll
    for (int j = 0; j < 4; j++) {
      int col = n0 + wn * 64 + j * 16 + r;
      float bv = bias[col];
#pragma unroll
      for (int reg = 0; reg < 4; reg++) {
        int rowg = m0 + wm * 128 + i * 16 + kq * 4 + reg;
        float val = acc[i][j][reg] + bv;
        if (EPI == 2) {
          float z2 = -1.5957691216057308f * fmaf(0.044715f * val, val * val, val);
          float gg = val / (1.f + __expf(z2));
          Cb[(size_t)rowg * N + col] = f2bf(gg);
        } else {
          Cb[(size_t)rowg * N + col] = f2bf(val);
        }
      }
    }
  }
}

// ---------------- GEMM: C[M,N] = A[M,K](bf16) @ B[N,K](bf16)^T + bias ----------------
// Round-3-proven 2-phase prefetch double-buffer, 4 waves, BK=64, zero-conflict swizzle.
// EPI 1: Cf += val + bias (residual accumulate, fp32)
template <int EPI, int BM, int BN>
__global__ __launch_bounds__(256) void gemm_bt(const u16* __restrict__ A,
                                               const u16* __restrict__ B,
                                               const float* __restrict__ bias,
                                               float* __restrict__ Cf,
                                               u16* __restrict__ Cb,
                                               int M, int N, int K) {
  constexpr int MI = BM / 32;
  constexpr int NJ = BN / 32;
  constexpr int ACH = BM * 64 / (256 * 8);
  constexpr int BCH = BN * 64 / (256 * 8);
  __shared__ u16 As[2][BM * 64];
  __shared__ u16 Bs[2][BN * 64];

  int gN = gridDim.x, gM = gridDim.y;
  int flat = blockIdx.x + gN * blockIdx.y;
  int nwg = gN * gM;
  int qc = nwg >> 3, rc = nwg & 7;
  int xcd = flat & 7, pos = flat >> 3;
  int start = (xcd < rc) ? xcd * (qc + 1) : rc * (qc + 1) + (xcd - rc) * qc;
  int swz = start + pos;
  int m0 = (swz % gM) * BM;
  int n0 = (swz / gM) * BN;

  int t = threadIdx.x, lane = t & 63, w = t >> 6;
  int wm = w >> 1, wn = w & 1;
  int r = lane & 15, kq = lane >> 4;
  f32x4 acc[MI][NJ] = {};

  auto stage = [&](int buf, int k0) {
#pragma unroll
    for (int i = 0; i < ACH; i++) {
      int chunk = i * 256 + t;
      int row = chunk >> 3, s = chunk & 7;
      int ss = s ^ (row & 7);
      GLOAD_LDS16(A + (size_t)(m0 + row) * K + k0 + ss * 8, &As[buf][chunk * 8]);
    }
#pragma unroll
    for (int i = 0; i < BCH; i++) {
      int chunk = i * 256 + t;
      int row = chunk >> 3, s = chunk & 7;
      int ss = s ^ (row & 7);
      GLOAD_LDS16(B + (size_t)(n0 + row) * K + k0 + ss * 8, &Bs[buf][chunk * 8]);
    }
  };

  auto compute = [&](int buf) {
#pragma unroll
    for (int kk = 0; kk < 64; kk += 32) {
      int sx8 = (((kk >> 3) + kq) ^ (r & 7)) * 8;
      bf16x8 af[MI], bfr[NJ];
#pragma unroll
      for (int i = 0; i < MI; i++)
        af[i] = *(const bf16x8*)&As[buf][(wm * (BM / 2) + i * 16 + r) * 64 + sx8];
#pragma unroll
      for (int j = 0; j < NJ; j++)
        bfr[j] = *(const bf16x8*)&Bs[buf][(wn * (BN / 2) + j * 16 + r) * 64 + sx8];
#pragma unroll
      for (int i = 0; i < MI; i++)
#pragma unroll
        for (int j = 0; j < NJ; j++)
          acc[i][j] = __builtin_amdgcn_mfma_f32_16x16x32_bf16(af[i], bfr[j], acc[i][j], 0, 0, 0);
    }
  };

  int NT = K >> 6;
  stage(0, 0);
  __syncthreads();
  for (int step = 0; step < NT; step++) {
    int buf = step & 1;
    if (step + 1 < NT) stage(buf ^ 1, (step + 1) * 64);
    compute(buf);
    __syncthreads();
  }

#pragma unroll
  for (int i = 0; i < MI; i++) {
#pragma unroll
    for (int j = 0; j < NJ; j++) {
      int col = n0 + wn * (BN / 2) + j * 16 + r;
      float bv = bias[col];
#pragma unroll
      for (int reg = 0; reg < 4; reg++) {
        int rowg = m0 + wm * (BM / 2) + i * 16 + kq * 4 + reg;
        float val = acc[i][j][reg] + bv;
        if (EPI == 1) {
          Cf[(size_t)rowg * N + col] += val;
        } else {
          Cb[(size_t)rowg * N + col] = f2bf(val);
        }
      }
    }
  }
}

// ---------------- RoPE + pack q,k into (NH, L, HDP) bf16, q scaled ----------------
__global__ __launch_bounds__(256) void rope_pack(const u16* __restrict__ qkv,
                                                 const float* __restrict__ rpe,
                                                 u16* __restrict__ qp,
                                                 u16* __restrict__ kp) {
  int l = blockIdx.x;
  int t = threadIdx.x;
  __shared__ float cs[40], sn[40];
  if (t < 40) {
    float a = rpe[l * 40 + t];
    cs[t] = cosf(a);
    sn[t] = sinf(a);
  }
  __syncthreads();
  const u16* row = qkv + (size_t)l * (3 * DMODEL);
  const float scale = 0.11180339887498949f;  // 1/sqrt(80)
#pragma unroll
  for (int i = 0; i < 5; i++) {
    int e = t + i * 256;
    int h = e / HDIM, d = e - h * HDIM;
    int dm = (d < 40) ? d : d - 40;
    float c = cs[dm], s = sn[dm];
    float qv = bf2f(row[h * HDIM + d]);
    float qr = (d < 40) ? -bf2f(row[h * HDIM + d + 40]) : bf2f(row[h * HDIM + d - 40]);
    qp[((size_t)h * LTOK + l) * HDP + d] = f2bf((qv * c + qr * s) * scale);
    float kv = bf2f(row[DMODEL + h * HDIM + d]);
    float kr = (d < 40) ? -bf2f(row[DMODEL + h * HDIM + d + 40]) : bf2f(row[DMODEL + h * HDIM + d - 40]);
    kp[((size_t)h * LTOK + l) * HDP + d] = f2bf(kv * c + kr * s);
  }
  // zero the pad [80,96)
  {
    int h = t >> 4, p = t & 15;
    qp[((size_t)h * LTOK + l) * HDP + HDIM + p] = 0;
    kp[((size_t)h * LTOK + l) * HDP + HDIM + p] = 0;
  }
}

// ---------------- V transpose: (L, NH, HD) bf16 slice of qkv -> (NH, HD, L) bf16 ----------------
__global__ __launch_bounds__(256) void vtrans(const u16* __restrict__ qkv,
                                              u16* __restrict__ vt) {
  int blk = blockIdx.x;
  int h = blk >> 5, lt = blk & 31;
  int t = threadIdx.x;
  __shared__ u16 ld[64][81];
#pragma unroll
  for (int i = 0; i < 20; i++) {
    int idx = t + i * 256;
    int ll = idx / HDIM, d = idx - ll * HDIM;
    ld[ll][d] = qkv[(size_t)(lt * 64 + ll) * (3 * DMODEL) + 2 * DMODEL + h * HDIM + d];
  }
  __syncthreads();
#pragma unroll
  for (int i = 0; i < 20; i++) {
    int idx = t + i * 256;
    int d = idx >> 6, ll = idx & 63;
    vt[((size_t)h * HDIM + d) * LTOK + lt * 64 + ll] = ld[ll][d];
  }
}

// ---------------- Attention: per (head, seg, 64-row q-tile) ----------------
__global__ __launch_bounds__(256) void attn(const u16* __restrict__ qp,
                                            const u16* __restrict__ kp,
                                            const u16* __restrict__ vt,
                                            u16* __restrict__ out) {
  int bid = blockIdx.x;               // h*32 + seg*8 + qt
  int h = bid >> 5;
  int seg = (bid >> 3) & 3;
  int qt = bid & 7;
  int t = threadIdx.x, w = t >> 6, lane = t & 63;
  int r = lane & 15, kq = lane >> 4;
  __shared__ u16 P[4][16][512];
  int seg0 = seg * SEGLEN;
  int q0 = seg0 + qt * 64 + w * 16;

  bf16x8 qf[3];
  const u16* qrow = qp + ((size_t)h * LTOK + q0 + r) * HDP;
#pragma unroll
  for (int kk = 0; kk < 3; kk++) qf[kk] = *(const bf16x8*)(qrow + kk * 32 + kq * 8);

  f32x4 sc[32];
#pragma unroll
  for (int j = 0; j < 32; j++) {
    f32x4 a = {0.f, 0.f, 0.f, 0.f};
    const u16* krow = kp + ((size_t)h * LTOK + seg0 + j * 16 + r) * HDP;
#pragma unroll
    for (int kk = 0; kk < 3; kk++) {
      bf16x8 bfr = *(const bf16x8*)(krow + kk * 32 + kq * 8);
      a = __builtin_amdgcn_mfma_f32_16x16x32_bf16(qf[kk], bfr, a, 0, 0, 0);
    }
    sc[j] = a;
  }

#pragma unroll
  for (int rr = 0; rr < 4; rr++) {
    float m = -1e30f;
#pragma unroll
    for (int j = 0; j < 32; j++) m = fmaxf(m, sc[j][rr]);
#pragma unroll
    for (int off = 1; off < 16; off <<= 1) m = fmaxf(m, __shfl_xor(m, off));
    float s = 0.f;
#pragma unroll
    for (int j = 0; j < 32; j++) { float e = __expf(sc[j][rr] - m); sc[j][rr] = e; s += e; }
#pragma unroll
    for (int off = 1; off < 16; off <<= 1) s += __shfl_xor(s, off);
    float inv = 1.f / s;
#pragma unroll
    for (int j = 0; j < 32; j++)
      P[w][kq * 4 + rr][j * 16 + r] = f2bf(sc[j][rr] * inv);
  }
  __syncthreads();

  f32x4 oc[5] = {};
#pragma unroll
  for (int tt = 0; tt < 16; tt++) {
    bf16x8 a = *(const bf16x8*)&P[w][r][tt * 32 + kq * 8];
#pragma unroll
    for (int n = 0; n < 5; n++) {
      const u16* vrow = vt + ((size_t)h * HDIM + n * 16 + r) * LTOK + seg0 + tt * 32 + kq * 8;
      bf16x8 bfr = *(const bf16x8*)vrow;
      oc[n] = __builtin_amdgcn_mfma_f32_16x16x32_bf16(a, bfr, oc[n], 0, 0, 0);
    }
  }
#pragma unroll
  for (int n = 0; n < 5; n++)
#pragma unroll
    for (int reg = 0; reg < 4; reg++) {
      int l = q0 + kq * 4 + reg;
      out[(size_t)l * DMODEL + h * HDIM + n * 16 + r] = f2bf(oc[n][reg]);
    }
}

// ---------------- host launch ----------------
extern "C" void kernel_launch(void* const* d_in, const int* in_sizes, int n_in,
                              void* d_out, int out_size, void* d_ws, size_t ws_size,
                              hipStream_t stream) {
  (void)in_sizes; (void)n_in; (void)out_size; (void)ws_size;
  const float* x_in   = (const float*)d_in[0];
  const float* rpe    = (const float*)d_in[1];
  const float* ln1_g  = (const float*)d_in[3];
  const float* ln1_b  = (const float*)d_in[4];
  const float* ln2_g  = (const float*)d_in[5];
  const float* ln2_b  = (const float*)d_in[6];
  const float* qkv_w  = (const float*)d_in[7];
  const float* qkv_b  = (const float*)d_in[8];
  const float* proj_w = (const float*)d_in[9];
  const float* proj_b = (const float*)d_in[10];
  const float* mlp_w1 = (const float*)d_in[11];
  const float* mlp_b1 = (const float*)d_in[12];
  const float* mlp_w2 = (const float*)d_in[13];
  const float* mlp_b2 = (const float*)d_in[14];
  float* x = (float*)d_out;

  char* ws = (char*)d_ws;
  size_t off = 0;
  auto alloc = [&](size_t bytes) -> char* {
    char* p = ws + off;
    off = (off + bytes + 255) & ~(size_t)255;
    return p;
  };
  u16* wq  = (u16*)alloc((size_t)3 * DMODEL * DMODEL * 2);
  u16* wp  = (u16*)alloc((size_t)DMODEL * DMODEL * 2);
  u16* w1  = (u16*)alloc((size_t)MLPD * DMODEL * 2);
  u16* w2  = (u16*)alloc((size_t)DMODEL * MLPD * 2);
  u16* hb  = (u16*)alloc((size_t)LTOK * DMODEL * 2);
  u16* qkvb = (u16*)alloc((size_t)LTOK * 3 * DMODEL * 2);
  u16* qp  = (u16*)alloc((size_t)NHEAD * LTOK * HDP * 2);
  u16* kp  = (u16*)alloc((size_t)NHEAD * LTOK * HDP * 2);
  u16* vt  = (u16*)alloc((size_t)NHEAD * HDIM * LTOK * 2);
  u16* att = (u16*)alloc((size_t)LTOK * DMODEL * 2);
  u16* ge  = (u16*)alloc((size_t)LTOK * MLPD * 2);

  hipMemcpyAsync(x, x_in, (size_t)LTOK * DMODEL * sizeof(float),
                 hipMemcpyDeviceToDevice, stream);

  for (int l = 0; l < NLAY; l++) {
    cvt4<<<(C3 + 255) / 256, 256, 0, stream>>>(
        qkv_w + (size_t)l * 3 * DMODEL * DMODEL, proj_w + (size_t)l * DMODEL * DMODEL,
        mlp_w1 + (size_t)l * MLPD * DMODEL, mlp_w2 + (size_t)l * DMODEL * MLPD,
        wq, wp, w1, w2);

    // LN1 -> h (bf16)
    ln_bf16<<<LTOK, 256, 0, stream>>>(x, ln1_g + l * DMODEL, ln1_b + l * DMODEL, hb);
    // QKV = h @ Wqkv^T + b (bf16 out): 256x256 deep-pipelined, grid 15x8 = 120 blocks
    gemm256<3><<<dim3(15, 8), 512, 0, stream>>>(
        hb, wq, qkv_b + (size_t)l * 3 * DMODEL, qkvb, LTOK, 3 * DMODEL, DMODEL);
    // RoPE + pack q,k ; transpose v
    rope_pack<<<LTOK, 256, 0, stream>>>(qkvb, rpe, qp, kp);
    vtrans<<<NHEAD * 32, 256, 0, stream>>>(qkvb, vt);
    // attention
    attn<<<NHEAD * 4 * 8, 256, 0, stream>>>(qp, kp, vt, att);
    // x += att @ Wproj^T + b   (64x64 2-phase, 640 blocks)
    gemm_bt<1, 64, 64><<<dim3(20, 32), 256, 0, stream>>>(
        att, wp, proj_b + (size_t)l * DMODEL, x, nullptr, LTOK, DMODEL, DMODEL);
    // LN2 -> h
    ln_bf16<<<LTOK, 256, 0, stream>>>(x, ln2_g + l * DMODEL, ln2_b + l * DMODEL, hb);
    // ge = gelu(h @ W1^T + b1): 256x256 deep-pipelined, grid 20x8 = 160 blocks
    gemm256<2><<<dim3(20, 8), 512, 0, stream>>>(
        hb, w1, mlp_b1 + (size_t)l * MLPD, ge, LTOK, MLPD, DMODEL);
    // x += ge @ W2^T + b2   (64x64 2-phase, 640 blocks)
    gemm_bt<1, 64, 64><<<dim3(20, 32), 256, 0, stream>>>(
        ge, w2, mlp_b2 + (size_t)l * DMODEL, x, nullptr, LTOK, DMODEL, MLPD);
  }
}

// Round 9
// 923.693 us; speedup vs baseline: 1.1700x; 1.0856x over previous
//
#include <hip/hip_runtime.h>
#include <cstdint>
#include <cstddef>

typedef unsigned short u16;
typedef __bf16 bf16_t;
typedef bf16_t bf16x8 __attribute__((ext_vector_type(8)));
typedef float f32x4 __attribute__((ext_vector_type(4)));

#define NLAY 4
#define DMODEL 1280
#define NHEAD 16
#define HDIM 80
#define HDP 96           // padded head dim for QK^T K-loop (3 x 32)
#define MLPD 5120
#define LTOK 2048
#define SEGLEN 512

__device__ __forceinline__ u16 f2bf(float f) {
  union { float f; unsigned u; } x; x.f = f;
  unsigned r = x.u + 0x7fffu + ((x.u >> 16) & 1u);
  return (u16)(r >> 16);
}
__device__ __forceinline__ float bf2f(u16 s) {
  union { unsigned u; float f; } x; x.u = ((unsigned)s) << 16;
  return x.f;
}

#define GLOAD_LDS16(gsrc, ldst) \
  __builtin_amdgcn_global_load_lds((const __attribute__((address_space(1))) void*)(gsrc), \
                                   (__attribute__((address_space(3))) void*)(ldst), 16, 0, 0)

__device__ __forceinline__ void barrier_mem() {
  asm volatile("s_barrier" ::: "memory");
}

// ---------------- all-weights fp32 -> bf16 convert (one layer, one kernel) ----------------
#define C0 (3 * DMODEL * DMODEL / 4)          // qkv_w float4s
#define C1 (C0 + DMODEL * DMODEL / 4)         // + proj_w
#define C2 (C1 + MLPD * DMODEL / 4)           // + mlp_w1
#define C3 (C2 + DMODEL * MLPD / 4)           // + mlp_w2
__global__ __launch_bounds__(256) void cvt4(const float* __restrict__ s_q,
                                            const float* __restrict__ s_p,
                                            const float* __restrict__ s_1,
                                            const float* __restrict__ s_2,
                                            u16* __restrict__ o_q, u16* __restrict__ o_p,
                                            u16* __restrict__ o_1, u16* __restrict__ o_2) {
  int i = blockIdx.x * 256 + threadIdx.x;
  const float* src; u16* dst; int off;
  if (i < C0)      { src = s_q; dst = o_q; off = i; }
  else if (i < C1) { src = s_p; dst = o_p; off = i - C0; }
  else if (i < C2) { src = s_1; dst = o_1; off = i - C1; }
  else if (i < C3) { src = s_2; dst = o_2; off = i - C2; }
  else return;
  const float4 v = reinterpret_cast<const float4*>(src)[off];
  union { u16 s[4]; uint2 u; } o;
  o.s[0] = f2bf(v.x); o.s[1] = f2bf(v.y); o.s[2] = f2bf(v.z); o.s[3] = f2bf(v.w);
  reinterpret_cast<uint2*>(dst)[off] = o.u;
}

// ---------------- LayerNorm (fp32 in, bf16 out) ----------------
__global__ __launch_bounds__(256) void ln_bf16(const float* __restrict__ x,
                                               const float* __restrict__ g,
                                               const float* __restrict__ b,
                                               u16* __restrict__ out) {
  int row = blockIdx.x;
  int t = threadIdx.x;
  const float* xr = x + (size_t)row * DMODEL;
  float v[5]; float s = 0.f, s2 = 0.f;
#pragma unroll
  for (int i = 0; i < 5; i++) { v[i] = xr[t + i * 256]; s += v[i]; s2 += v[i] * v[i]; }
#pragma unroll
  for (int off = 32; off; off >>= 1) { s += __shfl_down(s, off); s2 += __shfl_down(s2, off); }
  __shared__ float ps[4], ps2[4];
  int w = t >> 6;
  if ((t & 63) == 0) { ps[w] = s; ps2[w] = s2; }
  __syncthreads();
  s = ps[0] + ps[1] + ps[2] + ps[3];
  s2 = ps2[0] + ps2[1] + ps2[2] + ps2[3];
  float mean = s * (1.f / DMODEL);
  float var = s2 * (1.f / DMODEL) - mean * mean;
  float inv = rsqrtf(var + 1e-6f);
#pragma unroll
  for (int i = 0; i < 5; i++) {
    int c = t + i * 256;
    out[(size_t)row * DMODEL + c] = f2bf((v[i] - mean) * inv * g[c] + b[c]);
  }
}

// ---------------- deep-pipelined GEMM: 128Mx256N, BK=32, 8 waves, 3-buf counted vmcnt ----
// C[M,N] = A[M,K](bf16) @ B[N,K](bf16)^T + bias. 8 waves 2M x 4N, wave-tile
// 64x64, acc[4][4]. LDS 72 KB -> 2 blocks/CU (launch_bounds(512,4)).
// Per K-tile (single phase): vmcnt(3)+barrier; 8 ds_read frags; stage tile
// kt+2 (3 gloads/thread); 16 MFMA in setprio cluster. vmcnt(3) = tile kt+1's
// 3 loads are the only ones newer than tile kt's (in-order retirement =>
// tile kt landed). vmcnt(0) only on the last tile. Buffer (kt+2)%3 was last
// read in iteration kt-1, whose frag-reads completed (lgkmcnt before MFMA)
// before this iteration's barrier -> race-free.
// BK=32 swizzle (round-7-verified, zero conflicts): slot ^= (row>>1)&3 on
// both the pre-swizzled global source and the ds_read slot.
// EPI 2: Cb = gelu(val + bias)  (bf16); EPI 3: Cb = val + bias (bf16)
template <int EPI>
__global__ __launch_bounds__(512, 4) void gemmhp(const u16* __restrict__ A,
                                                 const u16* __restrict__ B,
                                                 const float* __restrict__ bias,
                                                 u16* __restrict__ Cb,
                                                 int M, int N, int K) {
  __shared__ u16 As[3][128 * 32];   // 24 KB
  __shared__ u16 Bs[3][256 * 32];   // 48 KB

  int gN = gridDim.x, gM = gridDim.y;
  int flat = blockIdx.x + gN * blockIdx.y;
  int nwg = gN * gM;
  int qc = nwg >> 3, rc = nwg & 7;
  int xcd = flat & 7, pos = flat >> 3;
  int start = (xcd < rc) ? xcd * (qc + 1) : rc * (qc + 1) + (xcd - rc) * qc;
  int swz = start + pos;
  int m0 = (swz % gM) * 128;
  int n0 = (swz / gM) * 256;

  int t = threadIdx.x, lane = t & 63, w = t >> 6;
  int wm = w >> 2, wn = w & 3;            // 2M x 4N waves, wave tile 64x64
  int r = lane & 15, kq = lane >> 4;
  f32x4 acc[4][4] = {};

  auto stageA = [&](int buf, int k0) {
    int row = t >> 2, s = t & 3;          // 512 chunks = 128 rows x 4 slots
    int ss = s ^ ((row >> 1) & 3);
    GLOAD_LDS16(A + (size_t)(m0 + row) * K + k0 + ss * 8, &As[buf][t * 8]);
  };
  auto stageB = [&](int buf, int k0) {
#pragma unroll
    for (int i = 0; i < 2; i++) {
      int chunk = i * 512 + t;            // 1024 chunks = 256 rows x 4 slots
      int row = chunk >> 2, s = chunk & 3;
      int ss = s ^ ((row >> 1) & 3);
      GLOAD_LDS16(B + (size_t)(n0 + row) * K + k0 + ss * 8, &Bs[buf][chunk * 8]);
    }
  };

  int NT = K >> 5;
  // prologue: tiles 0 and 1 staged (6 loads/thread in flight)
  stageA(0, 0); stageB(0, 0);
  stageA(1, 32); stageB(1, 32);

  int bt = 0;
  for (int kt = 0; kt < NT; kt++) {
    if (kt == NT - 1) asm volatile("s_waitcnt vmcnt(0)" ::: "memory");
    else              asm volatile("s_waitcnt vmcnt(3)" ::: "memory");
    barrier_mem();                       // tile kt landed chip-wide
    const u16* as = As[bt];
    const u16* bs = Bs[bt];
    int b2 = bt + 2; if (b2 >= 3) b2 -= 3;
    bool st = (kt + 2) < NT;
    int k2 = (kt + 2) << 5;

    bf16x8 af[4], bfv[4];
#pragma unroll
    for (int i = 0; i < 4; i++) {
      int row = wm * 64 + i * 16 + r;
      int ss = kq ^ ((row >> 1) & 3);
      af[i] = *(const bf16x8*)&as[row * 32 + ss * 8];
    }
#pragma unroll
    for (int j = 0; j < 4; j++) {
      int row = wn * 64 + j * 16 + r;
      int ss = kq ^ ((row >> 1) & 3);
      bfv[j] = *(const bf16x8*)&bs[row * 32 + ss * 8];
    }
    if (st) { stageA(b2, k2); stageB(b2, k2); }
    __builtin_amdgcn_s_setprio(1);
#pragma unroll
    for (int i = 0; i < 4; i++)
#pragma unroll
      for (int j = 0; j < 4; j++)
        acc[i][j] = __builtin_amdgcn_mfma_f32_16x16x32_bf16(af[i], bfv[j], acc[i][j], 0, 0, 0);
    __builtin_amdgcn_s_setprio(0);

    bt++; if (bt == 3) bt = 0;
  }

#pragma unroll
  for (int i = 0; i < 4; i++) {
#pragma unroll
    for (int j = 0; j < 4; j++) {
      int col = n0 + wn * 64 + j * 16 + r;
      float bv = bias[col];
#pragma unroll
      for (int reg = 0; reg < 4; reg++) {
        int rowg = m0 + wm * 64 + i * 16 + kq * 4 + reg;
        float val = acc[i][j][reg] + bv;
        if (EPI == 2) {
          float z2 = -1.5957691216057308f * fmaf(0.044715f * val, val * val, val);
          float gg = val / (1.f + __expf(z2));
          Cb[(size_t)rowg * N + col] = f2bf(gg);
        } else {
          Cb[(size_t)rowg * N + col] = f2bf(val);
        }
      }
    }
  }
}

// ---------------- GEMM: C[M,N] = A[M,K](bf16) @ B[N,K](bf16)^T + bias ----------------
// Round-3-proven 2-phase prefetch double-buffer, 4 waves, BK=64, zero-conflict swizzle.
// EPI 1: Cf += val + bias (residual accumulate, fp32)
template <int EPI, int BM, int BN>
__global__ __launch_bounds__(256) void gemm_bt(const u16* __restrict__ A,
                                               const u16* __restrict__ B,
                                               const float* __restrict__ bias,
                                               float* __restrict__ Cf,
                                               u16* __restrict__ Cb,
                                               int M, int N, int K) {
  constexpr int MI = BM / 32;
  constexpr int NJ = BN / 32;
  constexpr int ACH = BM * 64 / (256 * 8);
  constexpr int BCH = BN * 64 / (256 * 8);
  __shared__ u16 As[2][BM * 64];
  __shared__ u16 Bs[2][BN * 64];

  int gN = gridDim.x, gM = gridDim.y;
  int flat = blockIdx.x + gN * blockIdx.y;
  int nwg = gN * gM;
  int qc = nwg >> 3, rc = nwg & 7;
  int xcd = flat & 7, pos = flat >> 3;
  int start = (xcd < rc) ? xcd * (qc + 1) : rc * (qc + 1) + (xcd - rc) * qc;
  int swz = start + pos;
  int m0 = (swz % gM) * BM;
  int n0 = (swz / gM) * BN;

  int t = threadIdx.x, lane = t & 63, w = t >> 6;
  int wm = w >> 1, wn = w & 1;
  int r = lane & 15, kq = lane >> 4;
  f32x4 acc[MI][NJ] = {};

  auto stage = [&](int buf, int k0) {
#pragma unroll
    for (int i = 0; i < ACH; i++) {
      int chunk = i * 256 + t;
      int row = chunk >> 3, s = chunk & 7;
      int ss = s ^ (row & 7);
      GLOAD_LDS16(A + (size_t)(m0 + row) * K + k0 + ss * 8, &As[buf][chunk * 8]);
    }
#pragma unroll
    for (int i = 0; i < BCH; i++) {
      int chunk = i * 256 + t;
      int row = chunk >> 3, s = chunk & 7;
      int ss = s ^ (row & 7);
      GLOAD_LDS16(B + (size_t)(n0 + row) * K + k0 + ss * 8, &Bs[buf][chunk * 8]);
    }
  };

  auto compute = [&](int buf) {
#pragma unroll
    for (int kk = 0; kk < 64; kk += 32) {
      int sx8 = (((kk >> 3) + kq) ^ (r & 7)) * 8;
      bf16x8 af[MI], bfr[NJ];
#pragma unroll
      for (int i = 0; i < MI; i++)
        af[i] = *(const bf16x8*)&As[buf][(wm * (BM / 2) + i * 16 + r) * 64 + sx8];
#pragma unroll
      for (int j = 0; j < NJ; j++)
        bfr[j] = *(const bf16x8*)&Bs[buf][(wn * (BN / 2) + j * 16 + r) * 64 + sx8];
#pragma unroll
      for (int i = 0; i < MI; i++)
#pragma unroll
        for (int j = 0; j < NJ; j++)
          acc[i][j] = __builtin_amdgcn_mfma_f32_16x16x32_bf16(af[i], bfr[j], acc[i][j], 0, 0, 0);
    }
  };

  int NT = K >> 6;
  stage(0, 0);
  __syncthreads();
  for (int step = 0; step < NT; step++) {
    int buf = step & 1;
    if (step + 1 < NT) stage(buf ^ 1, (step + 1) * 64);
    compute(buf);
    __syncthreads();
  }

#pragma unroll
  for (int i = 0; i < MI; i++) {
#pragma unroll
    for (int j = 0; j < NJ; j++) {
      int col = n0 + wn * (BN / 2) + j * 16 + r;
      float bv = bias[col];
#pragma unroll
      for (int reg = 0; reg < 4; reg++) {
        int rowg = m0 + wm * (BM / 2) + i * 16 + kq * 4 + reg;
        float val = acc[i][j][reg] + bv;
        if (EPI == 1) {
          Cf[(size_t)rowg * N + col] += val;
        } else {
          Cb[(size_t)rowg * N + col] = f2bf(val);
        }
      }
    }
  }
}

// ---------------- RoPE + pack q,k into (NH, L, HDP) bf16, q scaled ----------------
__global__ __launch_bounds__(256) void rope_pack(const u16* __restrict__ qkv,
                                                 const float* __restrict__ rpe,
                                                 u16* __restrict__ qp,
                                                 u16* __restrict__ kp) {
  int l = blockIdx.x;
  int t = threadIdx.x;
  __shared__ float cs[40], sn[40];
  if (t < 40) {
    float a = rpe[l * 40 + t];
    cs[t] = cosf(a);
    sn[t] = sinf(a);
  }
  __syncthreads();
  const u16* row = qkv + (size_t)l * (3 * DMODEL);
  const float scale = 0.11180339887498949f;  // 1/sqrt(80)
#pragma unroll
  for (int i = 0; i < 5; i++) {
    int e = t + i * 256;
    int h = e / HDIM, d = e - h * HDIM;
    int dm = (d < 40) ? d : d - 40;
    float c = cs[dm], s = sn[dm];
    float qv = bf2f(row[h * HDIM + d]);
    float qr = (d < 40) ? -bf2f(row[h * HDIM + d + 40]) : bf2f(row[h * HDIM + d - 40]);
    qp[((size_t)h * LTOK + l) * HDP + d] = f2bf((qv * c + qr * s) * scale);
    float kv = bf2f(row[DMODEL + h * HDIM + d]);
    float kr = (d < 40) ? -bf2f(row[DMODEL + h * HDIM + d + 40]) : bf2f(row[DMODEL + h * HDIM + d - 40]);
    kp[((size_t)h * LTOK + l) * HDP + d] = f2bf(kv * c + kr * s);
  }
  // zero the pad [80,96)
  {
    int h = t >> 4, p = t & 15;
    qp[((size_t)h * LTOK + l) * HDP + HDIM + p] = 0;
    kp[((size_t)h * LTOK + l) * HDP + HDIM + p] = 0;
  }
}

// ---------------- V transpose: (L, NH, HD) bf16 slice of qkv -> (NH, HD, L) bf16 ----------------
__global__ __launch_bounds__(256) void vtrans(const u16* __restrict__ qkv,
                                              u16* __restrict__ vt) {
  int blk = blockIdx.x;
  int h = blk >> 5, lt = blk & 31;
  int t = threadIdx.x;
  __shared__ u16 ld[64][81];
#pragma unroll
  for (int i = 0; i < 20; i++) {
    int idx = t + i * 256;
    int ll = idx / HDIM, d = idx - ll * HDIM;
    ld[ll][d] = qkv[(size_t)(lt * 64 + ll) * (3 * DMODEL) + 2 * DMODEL + h * HDIM + d];
  }
  __syncthreads();
#pragma unroll
  for (int i = 0; i < 20; i++) {
    int idx = t + i * 256;
    int d = idx >> 6, ll = idx & 63;
    vt[((size_t)h * HDIM + d) * LTOK + lt * 64 + ll] = ld[ll][d];
  }
}

// ---------------- Attention: per (head, seg, 64-row q-tile) ----------------
__global__ __launch_bounds__(256) void attn(const u16* __restrict__ qp,
                                            const u16* __restrict__ kp,
                                            const u16* __restrict__ vt,
                                            u16* __restrict__ out) {
  int bid = blockIdx.x;               // h*32 + seg*8 + qt
  int h = bid >> 5;
  int seg = (bid >> 3) & 3;
  int qt = bid & 7;
  int t = threadIdx.x, w = t >> 6, lane = t & 63;
  int r = lane & 15, kq = lane >> 4;
  __shared__ u16 P[4][16][512];
  int seg0 = seg * SEGLEN;
  int q0 = seg0 + qt * 64 + w * 16;

  bf16x8 qf[3];
  const u16* qrow = qp + ((size_t)h * LTOK + q0 + r) * HDP;
#pragma unroll
  for (int kk = 0; kk < 3; kk++) qf[kk] = *(const bf16x8*)(qrow + kk * 32 + kq * 8);

  f32x4 sc[32];
#pragma unroll
  for (int j = 0; j < 32; j++) {
    f32x4 a = {0.f, 0.f, 0.f, 0.f};
    const u16* krow = kp + ((size_t)h * LTOK + seg0 + j * 16 + r) * HDP;
#pragma unroll
    for (int kk = 0; kk < 3; kk++) {
      bf16x8 bfr = *(const bf16x8*)(krow + kk * 32 + kq * 8);
      a = __builtin_amdgcn_mfma_f32_16x16x32_bf16(qf[kk], bfr, a, 0, 0, 0);
    }
    sc[j] = a;
  }

#pragma unroll
  for (int rr = 0; rr < 4; rr++) {
    float m = -1e30f;
#pragma unroll
    for (int j = 0; j < 32; j++) m = fmaxf(m, sc[j][rr]);
#pragma unroll
    for (int off = 1; off < 16; off <<= 1) m = fmaxf(m, __shfl_xor(m, off));
    float s = 0.f;
#pragma unroll
    for (int j = 0; j < 32; j++) { float e = __expf(sc[j][rr] - m); sc[j][rr] = e; s += e; }
#pragma unroll
    for (int off = 1; off < 16; off <<= 1) s += __shfl_xor(s, off);
    float inv = 1.f / s;
#pragma unroll
    for (int j = 0; j < 32; j++)
      P[w][kq * 4 + rr][j * 16 + r] = f2bf(sc[j][rr] * inv);
  }
  __syncthreads();

  f32x4 oc[5] = {};
#pragma unroll
  for (int tt = 0; tt < 16; tt++) {
    bf16x8 a = *(const bf16x8*)&P[w][r][tt * 32 + kq * 8];
#pragma unroll
    for (int n = 0; n < 5; n++) {
      const u16* vrow = vt + ((size_t)h * HDIM + n * 16 + r) * LTOK + seg0 + tt * 32 + kq * 8;
      bf16x8 bfr = *(const bf16x8*)vrow;
      oc[n] = __builtin_amdgcn_mfma_f32_16x16x32_bf16(a, bfr, oc[n], 0, 0, 0);
    }
  }
#pragma unroll
  for (int n = 0; n < 5; n++)
#pragma unroll
    for (int reg = 0; reg < 4; reg++) {
      int l = q0 + kq * 4 + reg;
      out[(size_t)l * DMODEL + h * HDIM + n * 16 + r] = f2bf(oc[n][reg]);
    }
}

// ---------------- host launch ----------------
extern "C" void kernel_launch(void* const* d_in, const int* in_sizes, int n_in,
                              void* d_out, int out_size, void* d_ws, size_t ws_size,
                              hipStream_t stream) {
  (void)in_sizes; (void)n_in; (void)out_size; (void)ws_size;
  const float* x_in   = (const float*)d_in[0];
  const float* rpe    = (const float*)d_in[1];
  const float* ln1_g  = (const float*)d_in[3];
  const float* ln1_b  = (const float*)d_in[4];
  const float* ln2_g  = (const float*)d_in[5];
  const float* ln2_b  = (const float*)d_in[6];
  const float* qkv_w  = (const float*)d_in[7];
  const float* qkv_b  = (const float*)d_in[8];
  const float* proj_w = (const float*)d_in[9];
  const float* proj_b = (const float*)d_in[10];
  const float* mlp_w1 = (const float*)d_in[11];
  const float* mlp_b1 = (const float*)d_in[12];
  const float* mlp_w2 = (const float*)d_in[13];
  const float* mlp_b2 = (const float*)d_in[14];
  float* x = (float*)d_out;

  char* ws = (char*)d_ws;
  size_t off = 0;
  auto alloc = [&](size_t bytes) -> char* {
    char* p = ws + off;
    off = (off + bytes + 255) & ~(size_t)255;
    return p;
  };
  u16* wq  = (u16*)alloc((size_t)3 * DMODEL * DMODEL * 2);
  u16* wp  = (u16*)alloc((size_t)DMODEL * DMODEL * 2);
  u16* w1  = (u16*)alloc((size_t)MLPD * DMODEL * 2);
  u16* w2  = (u16*)alloc((size_t)DMODEL * MLPD * 2);
  u16* hb  = (u16*)alloc((size_t)LTOK * DMODEL * 2);
  u16* qkvb = (u16*)alloc((size_t)LTOK * 3 * DMODEL * 2);
  u16* qp  = (u16*)alloc((size_t)NHEAD * LTOK * HDP * 2);
  u16* kp  = (u16*)alloc((size_t)NHEAD * LTOK * HDP * 2);
  u16* vt  = (u16*)alloc((size_t)NHEAD * HDIM * LTOK * 2);
  u16* att = (u16*)alloc((size_t)LTOK * DMODEL * 2);
  u16* ge  = (u16*)alloc((size_t)LTOK * MLPD * 2);

  hipMemcpyAsync(x, x_in, (size_t)LTOK * DMODEL * sizeof(float),
                 hipMemcpyDeviceToDevice, stream);

  for (int l = 0; l < NLAY; l++) {
    cvt4<<<(C3 + 255) / 256, 256, 0, stream>>>(
        qkv_w + (size_t)l * 3 * DMODEL * DMODEL, proj_w + (size_t)l * DMODEL * DMODEL,
        mlp_w1 + (size_t)l * MLPD * DMODEL, mlp_w2 + (size_t)l * DMODEL * MLPD,
        wq, wp, w1, w2);

    // LN1 -> h (bf16)
    ln_bf16<<<LTOK, 256, 0, stream>>>(x, ln1_g + l * DMODEL, ln1_b + l * DMODEL, hb);
    // QKV = h @ Wqkv^T + b (bf16 out): 128x256 deep-pipelined, grid 15x16 = 240 blocks
    gemmhp<3><<<dim3(15, 16), 512, 0, stream>>>(
        hb, wq, qkv_b + (size_t)l * 3 * DMODEL, qkvb, LTOK, 3 * DMODEL, DMODEL);
    // RoPE + pack q,k ; transpose v
    rope_pack<<<LTOK, 256, 0, stream>>>(qkvb, rpe, qp, kp);
    vtrans<<<NHEAD * 32, 256, 0, stream>>>(qkvb, vt);
    // attention
    attn<<<NHEAD * 4 * 8, 256, 0, stream>>>(qp, kp, vt, att);
    // x += att @ Wproj^T + b   (64x64 2-phase, 640 blocks)
    gemm_bt<1, 64, 64><<<dim3(20, 32), 256, 0, stream>>>(
        att, wp, proj_b + (size_t)l * DMODEL, x, nullptr, LTOK, DMODEL, DMODEL);
    // LN2 -> h
    ln_bf16<<<LTOK, 256, 0, stream>>>(x, ln2_g + l * DMODEL, ln2_b + l * DMODEL, hb);
    // ge = gelu(h @ W1^T + b1): 128x256 deep-pipelined, grid 20x16 = 320 blocks
    gemmhp<2><<<dim3(20, 16), 512, 0, stream>>>(
        hb, w1, mlp_b1 + (size_t)l * MLPD, ge, LTOK, MLPD, DMODEL);
    // x += ge @ W2^T + b2   (64x64 2-phase, 640 blocks)
    gemm_bt<1, 64, 64><<<dim3(20, 32), 256, 0, stream>>>(
        ge, w2, mlp_b2 + (size_t)l * DMODEL, x, nullptr, LTOK, DMODEL, MLPD);
  }
}